// Round 10
// baseline (455.033 us; speedup 1.0000x reference)
//
#include <hip/hip_runtime.h>
#include <hip/hip_bf16.h>

#define DIV_UP(a,b) (((a)+(b)-1)/(b))

typedef __attribute__((ext_vector_type(8))) short short8;
typedef __attribute__((ext_vector_type(4))) float f32x4;

__device__ __forceinline__ ushort bf16_bits(float x) {
    return __builtin_bit_cast(ushort, __float2bfloat16(x));
}

// ---------------------------------------------------------------------------
// Zero ONLY the pad halos (top row + left col) of act1/act2 and vbuf.
// ---------------------------------------------------------------------------
__global__ __launch_bounds__(256) void halo_zero_kernel(
    uint4* __restrict__ act1, uint4* __restrict__ act2,
    float4* __restrict__ vbuf) {
    const int b = blockIdx.x, tid = threadIdx.x;
    const uint4 z = {0u, 0u, 0u, 0u};
    uint4* a1 = act1 + (size_t)b * 33800;          // 65*65*64 bf16 = 33800 uint4
    for (int i = tid; i < 520; i += 256) a1[i] = z;
    for (int i = tid; i < 512; i += 256) {
        int r = (i >> 3) + 1;
        a1[r * 520 + (i & 7)] = z;
    }
    uint4* a2 = act2 + (size_t)b * 17424;          // 33*33*128 bf16 = 17424 uint4
    for (int i = tid; i < 528; i += 256) a2[i] = z;
    for (int i = tid; i < 512; i += 256) {
        int r = (i >> 4) + 1;
        a2[r * 528 + (i & 15)] = z;
    }
    int idx = b * 256 + tid;
    float4 zf = {0.f, 0.f, 0.f, 0.f};
    if (idx < 16384) vbuf[idx] = zf;
}

// ---------------------------------------------------------------------------
// conv1 weights OIHW [64,3,3,3] -> fp32 [27][64]
// ---------------------------------------------------------------------------
__global__ void transpose_w1_kernel(const float* __restrict__ src,
                                    float* __restrict__ dst) {
    int t = blockIdx.x * blockDim.x + threadIdx.x;
    if (t >= 1728) return;
    int oc = t % 64;
    int r  = t / 64;
    int q  = r % 9;
    int c  = r / 9;
    dst[t] = src[(oc * 3 + c) * 9 + q];
}

// ---------------------------------------------------------------------------
// conv2/3 weights OIHW [O][C][9] fp32 -> bf16 [O][9*C], k = tap*C + c
// ---------------------------------------------------------------------------
__global__ void repack_w_kernel(const float* __restrict__ src,
                                __hip_bfloat16* __restrict__ dst, int O, int C) {
    int t = blockIdx.x * blockDim.x + threadIdx.x;
    if (t >= O * C * 9) return;
    int o   = t / (C * 9);
    int r   = t % (C * 9);
    int tap = r / C;
    int c   = r % C;
    dst[t] = __float2bfloat16(src[(o * C + c) * 9 + tap]);
}

// ---------------------------------------------------------------------------
// conv1: fp32 NCHW [CHI,3,128,128] -> bf16 padded NHWC [CHI,65,65,64], ReLU
// ---------------------------------------------------------------------------
__global__ __launch_bounds__(256) void conv1_kernel(
    const float* __restrict__ in, const float* __restrict__ wt /*[27][64]*/,
    const float* __restrict__ bias, __hip_bfloat16* __restrict__ out) {
    const int tid  = threadIdx.x;
    const int lane = tid & 63;          // ow
    const int wv   = tid >> 6;          // oc group 0..3
    const int oh   = blockIdx.x;        // 0..63
    const int b    = blockIdx.y;

    __shared__ float  sx[3][3][132];
    __shared__ ushort sc[64][72];

    const float* ip  = in + (size_t)b * 3 * 128 * 128;
    const int    ih0 = 2 * oh - 1;
    for (int e = tid; e < 1170; e += 256) {
        int c   = e / 390;
        int rem = e - c * 390;
        int r   = rem / 130;
        int col = rem - r * 130;
        int ih  = ih0 + r;
        int iw  = col - 1;
        bool ok = ((unsigned)ih < 128u) && ((unsigned)iw < 128u);
        sx[c][r][col] = ok ? ip[c * 16384 + ih * 128 + iw] : 0.f;
    }
    __syncthreads();

    const int oc0 = __builtin_amdgcn_readfirstlane(wv << 4);
    const float* wts = wt + oc0;
    float acc[16];
#pragma unroll
    for (int i = 0; i < 16; ++i) acc[i] = bias[oc0 + i];
#pragma unroll
    for (int c = 0; c < 3; ++c)
#pragma unroll
        for (int kh = 0; kh < 3; ++kh)
#pragma unroll
            for (int kw = 0; kw < 3; ++kw) {
                float x = sx[c][kh][2 * lane + kw];
                const float* wrow = wts + (c * 9 + kh * 3 + kw) * 64;
#pragma unroll
                for (int i = 0; i < 16; ++i) acc[i] = fmaf(x, wrow[i], acc[i]);
            }

#pragma unroll
    for (int h = 0; h < 2; ++h) {
        union { uint4 u4; ushort s[8]; } pk;
#pragma unroll
        for (int e = 0; e < 8; ++e)
            pk.s[e] = bf16_bits(fmaxf(acc[h * 8 + e], 0.f));
        *(uint4*)&sc[lane][oc0 + h * 8] = pk.u4;
    }
    __syncthreads();

    __hip_bfloat16* obase = out + (((size_t)b * 65 + oh + 1) * 65 + 1) * 64;
#pragma unroll
    for (int s = 0; s < 2; ++s) {
        int g   = tid * 32 + s * 16;
        int pix = g >> 7;
        int col = (g & 127) >> 1;
        uint4 val = *(const uint4*)&sc[pix][col];
        *(uint4*)((char*)obase + g) = val;
    }
}

// ---------------------------------------------------------------------------
// conv2 implicit-GEMM, barrier-free K-loop:
// The block's entire 9-row x 65-px input region (per 32-ch half) is staged
// ONCE into LDS (XOR-swizzled for conflict-spread fragment reads), then all
// 9 taps run with A from LDS and B directly global->VGPR (wtB is L2-hot) —
// no __syncthreads inside the tap loop, so the compiler pipelines freely.
// M-tile 128 (4 oh-rows x 32 ow, single image), N = 128. 2 ch-half passes.
// ---------------------------------------------------------------------------
__global__ __launch_bounds__(256, 2) void conv2_gemm_kernel(
    const __hip_bfloat16* __restrict__ act,
    const __hip_bfloat16* __restrict__ wtB,   // [128][576]
    const float* __restrict__ bias,
    __hip_bfloat16* __restrict__ out) {
    const int tid  = threadIdx.x;
    const int lane = tid & 63;
    const int w    = tid >> 6;
    const int l15  = lane & 15;
    const int quad = lane >> 4;
    const int per  = gridDim.x >> 3;
    const int Mt   = (blockIdx.x & 7) * per + (blockIdx.x >> 3);
    const int bimg = Mt >> 3;
    const int oh0  = (Mt & 7) << 2;

    __shared__ __align__(16) char smem[37504];   // 585 px * 64 B = 37440
    ushort* As = (ushort*)smem;                  // [p][seg^] 32 elem/px
    ushort* Cs = (ushort*)smem;                  // epilogue alias (33792 B)

    f32x4 acc[4][4];
#pragma unroll
    for (int i = 0; i < 4; ++i)
#pragma unroll
        for (int j = 0; j < 4; ++j) acc[i][j] = (f32x4){0.f, 0.f, 0.f, 0.f};

    const int wm = (w & 1) << 6;
    const int wn = (w >> 1) << 6;
    const size_t abase = ((size_t)(bimg * 65 + 2 * oh0)) * 65 * 64;

    for (int h = 0; h < 2; ++h) {
        __syncthreads();   // previous pass's LDS reads complete
        // stage 9 rows x 65 px x 32 ch = 2340 16B chunks, XOR-swizzled
#pragma unroll
        for (int it = 0; it < 10; ++it) {
            int e = tid + (it << 8);
            if (e < 2340) {
                int s = e & 3, p = e >> 2;            // p = r*65 + px
                uint4 val = *(const uint4*)(act + abase + (size_t)p * 64 +
                                            h * 32 + s * 8);
                *(uint4*)(As + p * 32 + ((s ^ (p & 3)) << 3)) = val;
            }
        }
        __syncthreads();
#pragma unroll
        for (int tap = 0; tap < 9; ++tap) {
            const int kh = tap / 3, kw = tap - kh * 3;
            short8 af[4], bf[4];
#pragma unroll
            for (int i = 0; i < 4; ++i) {
                int ml = wm + i * 16 + l15;
                int p  = ((ml >> 5) * 2 + kh) * 65 + ((ml & 31) * 2 + kw);
                af[i] = __builtin_bit_cast(short8,
                    *(const uint4*)(As + p * 32 + ((quad ^ (p & 3)) << 3)));
            }
#pragma unroll
            for (int j = 0; j < 4; ++j)
                bf[j] = __builtin_bit_cast(short8,
                    *(const uint4*)(wtB + (size_t)(wn + j * 16 + l15) * 576 +
                                    tap * 64 + h * 32 + quad * 8));
#pragma unroll
            for (int i = 0; i < 4; ++i)
#pragma unroll
                for (int j = 0; j < 4; ++j)
                    acc[i][j] = __builtin_amdgcn_mfma_f32_16x16x32_bf16(
                        af[i], bf[j], acc[i][j], 0, 0, 0);
        }
    }

    // epilogue: bias+ReLU -> bf16 tile in LDS -> coalesced 8B stores
    __syncthreads();
#pragma unroll
    for (int j = 0; j < 4; ++j) {
        int n = wn + j * 16 + l15;
        float bv = bias[n];
#pragma unroll
        for (int i = 0; i < 4; ++i)
#pragma unroll
            for (int r = 0; r < 4; ++r) {
                int ml = wm + i * 16 + quad * 4 + r;
                Cs[ml * 132 + n] = bf16_bits(fmaxf(acc[i][j][r] + bv, 0.f));
            }
    }
    __syncthreads();
#pragma unroll
    for (int q = 0; q < 16; ++q) {
        int c   = tid + 256 * q;
        int row = c >> 5;
        int off = c & 31;
        uint2 val = *(const uint2*)(Cs + row * 132 + off * 4);
        int m  = (Mt << 7) + row;
        int b  = m >> 10;
        int rr = m & 1023;
        int oh = rr >> 5;
        int ow = rr & 31;
        size_t pix = ((size_t)(b * 33 + oh + 1) * 33 + (ow + 1));
        *(uint2*)(out + pix * 128 + off * 4) = val;
    }
}

// ---------------------------------------------------------------------------
// conv3 implicit-GEMM + fused pool, barrier-free K-loop (same scheme):
// M-tile 64 (4 oh-rows x 16 ow), N = 256 (full), 2 ch-half passes of 64 ch.
// LDS = 9 rows x 33 px x 64 ch = 38016 B. B direct from global (L2-hot).
// ---------------------------------------------------------------------------
__global__ __launch_bounds__(256, 2) void conv3_gemm_pool_kernel(
    const __hip_bfloat16* __restrict__ act,
    const __hip_bfloat16* __restrict__ wtB,   // [256][1152]
    const float* __restrict__ bias,
    float* __restrict__ v /* [CHI,256], pre-zeroed */) {
    const int tid  = threadIdx.x;
    const int lane = tid & 63;
    const int w    = tid >> 6;
    const int l15  = lane & 15;
    const int quad = lane >> 4;
    const int per  = gridDim.x >> 3;
    const int Mt   = (blockIdx.x & 7) * per + (blockIdx.x >> 3);
    const int bimg = Mt >> 2;
    const int oh0  = (Mt & 3) << 2;

    __shared__ __align__(16) char smem[38016];   // 297 px * 128 B
    ushort* As   = (ushort*)smem;
    float*  sred = (float*)smem;                 // pool alias (1 KB)

    f32x4 acc[4][4];
#pragma unroll
    for (int i = 0; i < 4; ++i)
#pragma unroll
        for (int j = 0; j < 4; ++j) acc[i][j] = (f32x4){0.f, 0.f, 0.f, 0.f};

    const int wn = w << 6;                       // wave owns 64 n-cols
    const size_t abase = ((size_t)(bimg * 33 + 2 * oh0)) * 33 * 128;

    for (int h = 0; h < 2; ++h) {
        __syncthreads();
        // stage 9 rows x 33 px x 64 ch = 2376 16B chunks, XOR-swizzled
#pragma unroll
        for (int it = 0; it < 10; ++it) {
            int e = tid + (it << 8);
            if (e < 2376) {
                int s = e & 7, p = e >> 3;           // p = r*33 + px
                uint4 val = *(const uint4*)(act + abase + (size_t)p * 128 +
                                            h * 64 + s * 8);
                *(uint4*)(As + p * 64 + ((s ^ (p & 7)) << 3)) = val;
            }
        }
        __syncthreads();
#pragma unroll
        for (int tap = 0; tap < 9; ++tap) {
            const int kh = tap / 3, kw = tap - kh * 3;
#pragma unroll
            for (int ks = 0; ks < 2; ++ks) {
                short8 af[4], bf[4];
                const int sg = ks * 4 + quad;
#pragma unroll
                for (int i = 0; i < 4; ++i) {
                    int p = (i * 2 + kh) * 33 + l15 * 2 + kw;
                    af[i] = __builtin_bit_cast(short8,
                        *(const uint4*)(As + p * 64 + ((sg ^ (p & 7)) << 3)));
                }
#pragma unroll
                for (int j = 0; j < 4; ++j)
                    bf[j] = __builtin_bit_cast(short8,
                        *(const uint4*)(wtB + (size_t)(wn + j * 16 + l15) * 1152 +
                                        tap * 128 + h * 64 + sg * 8));
#pragma unroll
                for (int i = 0; i < 4; ++i)
#pragma unroll
                    for (int j = 0; j < 4; ++j)
                        acc[i][j] = __builtin_amdgcn_mfma_f32_16x16x32_bf16(
                            af[i], bf[j], acc[i][j], 0, 0, 0);
            }
        }
    }

    // fused pool: bias+ReLU, sum over the block's 64 spatial positions
    float s4[4];
#pragma unroll
    for (int j = 0; j < 4; ++j) {
        float bv = bias[wn + j * 16 + l15];
        float s = 0.f;
#pragma unroll
        for (int i = 0; i < 4; ++i)
#pragma unroll
            for (int r = 0; r < 4; ++r)
                s += fmaxf(acc[i][j][r] + bv, 0.f);
        s += __shfl_xor(s, 16, 64);   // reduce across quads (same n)
        s += __shfl_xor(s, 32, 64);
        s4[j] = s;
    }
    __syncthreads();   // all K-loop LDS reads done before sred alias write
    if (quad == 0) {
#pragma unroll
        for (int j = 0; j < 4; ++j) sred[wn + j * 16 + l15] = s4[j];
    }
    __syncthreads();
    atomicAdd(v + (size_t)bimg * 256 + tid, sred[tid] * (1.f / 256.f));
}

// ---------------------------------------------------------------------------
// Tail: one block (256 thr) per sample; K-split GEMV stages, float4 weights.
// ---------------------------------------------------------------------------
template<int N, int K, int S, bool RELU>
__device__ __forceinline__ void gemv_stage(const float* __restrict__ w,
                                           const float* __restrict__ bias,
                                           const float* in, float* outv,
                                           float4* red4, int tid) {
    constexpr int G = N / 4;
    constexpr int CHK = K / S;
    static_assert(G * S == 256 && CHK * S == K, "stage shape");
    const int g = tid % G, s = tid / G;
    const float4* wp = (const float4*)w;
    float4 a; a.x = a.y = a.z = a.w = 0.f;
    const int k0 = s * CHK;
#pragma unroll 8
    for (int i = 0; i < CHK; ++i) {
        float x = in[k0 + i];
        float4 wv = wp[(size_t)(k0 + i) * G + g];
        a.x = fmaf(x, wv.x, a.x);
        a.y = fmaf(x, wv.y, a.y);
        a.z = fmaf(x, wv.z, a.z);
        a.w = fmaf(x, wv.w, a.w);
    }
    red4[tid] = a;
    __syncthreads();
    if (tid < N) {
        int gg = tid >> 2, e = tid & 3;
        float vv = bias[tid];
#pragma unroll
        for (int ss = 0; ss < S; ++ss) {
            const float* rp = (const float*)(red4 + ss * G + gg);
            vv += rp[e];
        }
        if (RELU) vv = fmaxf(vv, 0.f);
        outv[tid] = vv;
    }
    __syncthreads();
}

__global__ __launch_bounds__(256) void tail_kernel(
    const float* __restrict__ prop, const int* __restrict__ task_ids,
    const float* __restrict__ p1_w, const float* __restrict__ p1_b,
    const float* __restrict__ p2_w, const float* __restrict__ p2_b,
    const float* __restrict__ v,
    const float* __restrict__ f1_w, const float* __restrict__ f1_b,
    const float* __restrict__ f2_w, const float* __restrict__ f2_b,
    const float* __restrict__ task_emb,
    const float* __restrict__ g_w, const float* __restrict__ g_b,
    const float* __restrict__ h1_w, const float* __restrict__ h1_b,
    const float* __restrict__ h2_w, const float* __restrict__ h2_b,
    const float* __restrict__ h3_w, const float* __restrict__ h3_b,
    float* __restrict__ out) {
    const int b   = blockIdx.x;
    const int tid = threadIdx.x;
    const int t   = task_ids[b];
    __shared__ float sa[320];
    __shared__ float sb[288];
    __shared__ float sph[64];
    __shared__ float4 red4[256];

    sa[tid] = (tid < 256) ? v[(size_t)b * 256 + tid] : 0.f;
    if (tid < 64) {
        float h = p1_b[tid];
#pragma unroll
        for (int k = 0; k < 7; ++k) h = fmaf(prop[b * 7 + k], p1_w[k * 64 + tid], h);
        sph[tid] = fmaxf(h, 0.f);
    }
    __syncthreads();
    gemv_stage<64, 64, 16, false>(p2_w, p2_b, sph, sa + 256, red4, tid);
    gemv_stage<256, 320, 4, true>(f1_w, f1_b, sa, sb, red4, tid);
    gemv_stage<256, 256, 4, true>(f2_w, f2_b, sb, sa, red4, tid);
    if (tid < 32) sa[256 + tid] = task_emb[t * 32 + tid];
    __syncthreads();
    gemv_stage<256, 288, 4, true>(g_w, g_b, sa, sb, red4, tid);
    gemv_stage<128, 256, 8, true>(h1_w + (size_t)t * 32768, h1_b + t * 128,
                                  sb, sa, red4, tid);
    gemv_stage<128, 128, 8, true>(h2_w + (size_t)t * 16384, h2_b + t * 128,
                                  sa, sb, red4, tid);
    if (tid < 128) {
        float4 wv = ((const float4*)(h3_w + (size_t)t * 512))[tid];
        float x = sb[tid];
        float r0 = x * wv.x, r1 = x * wv.y, r2 = x * wv.z, r3 = x * wv.w;
#pragma unroll
        for (int off = 1; off < 64; off <<= 1) {
            r0 += __shfl_xor(r0, off, 64);
            r1 += __shfl_xor(r1, off, 64);
            r2 += __shfl_xor(r2, off, 64);
            r3 += __shfl_xor(r3, off, 64);
        }
        if ((tid & 63) == 0) {
            float4 rv; rv.x = r0; rv.y = r1; rv.z = r2; rv.w = r3;
            red4[tid >> 6] = rv;
        }
    }
    __syncthreads();
    if (tid < 4) {
        const float* ra = (const float*)(red4 + 0);
        const float* rb = (const float*)(red4 + 1);
        out[b * 4 + tid] = ra[tid] + rb[tid] + h3_b[t * 4 + tid];
    }
}

// ---------------------------------------------------------------------------
extern "C" void kernel_launch(void* const* d_in, const int* in_sizes, int n_in,
                              void* d_out, int out_size, void* d_ws, size_t ws_size,
                              hipStream_t stream) {
    (void)in_sizes; (void)n_in; (void)out_size;
    const float* images   = (const float*)d_in[0];
    const float* prop     = (const float*)d_in[1];
    const int*   task_ids = (const int*)d_in[2];
    const float* c1_w = (const float*)d_in[3];
    const float* c1_b = (const float*)d_in[4];
    const float* c2_w = (const float*)d_in[5];
    const float* c2_b = (const float*)d_in[6];
    const float* c3_w = (const float*)d_in[7];
    const float* c3_b = (const float*)d_in[8];
    const float* p1_w = (const float*)d_in[9];
    const float* p1_b = (const float*)d_in[10];
    const float* p2_w = (const float*)d_in[11];
    const float* p2_b = (const float*)d_in[12];
    const float* f1_w = (const float*)d_in[13];
    const float* f1_b = (const float*)d_in[14];
    const float* f2_w = (const float*)d_in[15];
    const float* f2_b = (const float*)d_in[16];
    const float* temb = (const float*)d_in[17];
    const float* g_w  = (const float*)d_in[18];
    const float* g_b  = (const float*)d_in[19];
    const float* h1_w = (const float*)d_in[20];
    const float* h1_b = (const float*)d_in[21];
    const float* h2_w = (const float*)d_in[22];
    const float* h2_b = (const float*)d_in[23];
    const float* h3_w = (const float*)d_in[24];
    const float* h3_b = (const float*)d_in[25];
    float* out = (float*)d_out;

    const size_t per_img = (size_t)65 * 65 * 64 * 2 + (size_t)33 * 33 * 128 * 2;
    const size_t fixed   = (size_t)256 * 256 * 4 + 1728 * 4 +
                           (size_t)73728 * 2 + (size_t)294912 * 2 + 4096;
    int CHI = 64;
    if (ws_size >= fixed + per_img * 256) CHI = 256;
    else if (ws_size >= fixed + per_img * 128) CHI = 128;

    char* ws = (char*)d_ws;
    size_t off = 0;
    auto alloc = [&](size_t bytes) {
        void* p = ws + off;
        off += (bytes + 255) & ~(size_t)255;
        return p;
    };
    __hip_bfloat16* act1 = (__hip_bfloat16*)alloc((size_t)CHI * 65 * 65 * 64 * 2);
    __hip_bfloat16* act2 = (__hip_bfloat16*)alloc((size_t)CHI * 33 * 33 * 128 * 2);
    float*          vbuf = (float*)alloc((size_t)256 * 256 * 4);
    float*          w1t  = (float*)alloc((size_t)1728 * 4);
    __hip_bfloat16* w2t  = (__hip_bfloat16*)alloc((size_t)73728 * 2);
    __hip_bfloat16* w3t  = (__hip_bfloat16*)alloc((size_t)294912 * 2);

    halo_zero_kernel<<<dim3(CHI), 256, 0, stream>>>(
        (uint4*)act1, (uint4*)act2, (float4*)vbuf);
    transpose_w1_kernel<<<DIV_UP(1728, 256), 256, 0, stream>>>(c1_w, w1t);
    repack_w_kernel<<<DIV_UP(73728, 256), 256, 0, stream>>>(c2_w, w2t, 128, 64);
    repack_w_kernel<<<DIV_UP(294912, 256), 256, 0, stream>>>(c3_w, w3t, 256, 128);

    for (int c0 = 0; c0 < 256; c0 += CHI) {
        const float* img_c = images + (size_t)c0 * 3 * 128 * 128;
        conv1_kernel<<<dim3(64, CHI), dim3(256), 0, stream>>>(
            img_c, w1t, c1_b, act1);
        conv2_gemm_kernel<<<dim3(CHI * 8), 256, 0, stream>>>(
            act1, w2t, c2_b, act2);
        conv3_gemm_pool_kernel<<<dim3(CHI * 4), 256, 0, stream>>>(
            act2, w3t, c3_b, vbuf + (size_t)c0 * 256);
    }
    tail_kernel<<<256, 256, 0, stream>>>(prop, task_ids, p1_w, p1_b, p2_w, p2_b,
                                         vbuf, f1_w, f1_b, f2_w, f2_b, temb,
                                         g_w, g_b, h1_w, h1_b, h2_w, h2_b,
                                         h3_w, h3_b, out);
}

// Round 11
// 375.345 us; speedup vs baseline: 1.2123x; 1.2123x over previous
//
#include <hip/hip_runtime.h>
#include <hip/hip_bf16.h>

#define DIV_UP(a,b) (((a)+(b)-1)/(b))

typedef __attribute__((ext_vector_type(8))) short short8;
typedef __attribute__((ext_vector_type(4))) float f32x4;

__device__ __forceinline__ ushort bf16_bits(float x) {
    return __builtin_bit_cast(ushort, __float2bfloat16(x));
}

// ---------------------------------------------------------------------------
// Zero ONLY the pad halos (top row + left col) of act1/act2 and vbuf.
// ---------------------------------------------------------------------------
__global__ __launch_bounds__(256) void halo_zero_kernel(
    uint4* __restrict__ act1, uint4* __restrict__ act2,
    float4* __restrict__ vbuf) {
    const int b = blockIdx.x, tid = threadIdx.x;
    const uint4 z = {0u, 0u, 0u, 0u};
    uint4* a1 = act1 + (size_t)b * 33800;          // 65*65*64 bf16 = 33800 uint4
    for (int i = tid; i < 520; i += 256) a1[i] = z;
    for (int i = tid; i < 512; i += 256) {
        int r = (i >> 3) + 1;
        a1[r * 520 + (i & 7)] = z;
    }
    uint4* a2 = act2 + (size_t)b * 17424;          // 33*33*128 bf16 = 17424 uint4
    for (int i = tid; i < 528; i += 256) a2[i] = z;
    for (int i = tid; i < 512; i += 256) {
        int r = (i >> 4) + 1;
        a2[r * 528 + (i & 15)] = z;
    }
    int idx = b * 256 + tid;
    float4 zf = {0.f, 0.f, 0.f, 0.f};
    if (idx < 16384) vbuf[idx] = zf;
}

// ---------------------------------------------------------------------------
// conv1 weights OIHW [64,3,3,3] -> fp32 [27][64]
// ---------------------------------------------------------------------------
__global__ void transpose_w1_kernel(const float* __restrict__ src,
                                    float* __restrict__ dst) {
    int t = blockIdx.x * blockDim.x + threadIdx.x;
    if (t >= 1728) return;
    int oc = t % 64;
    int r  = t / 64;
    int q  = r % 9;
    int c  = r / 9;
    dst[t] = src[(oc * 3 + c) * 9 + q];
}

// ---------------------------------------------------------------------------
// conv weights OIHW [O][C][9] fp32 -> bf16 [tap][C/8][O][8]:
// dst[((tap*SEG + sg)*O + n)*8 + e] = W[n][sg*8+e][tap]  (SEG = C/8)
// -> GEMM B fragment loads are lane-consecutive (coalesced 16B/lane).
// ---------------------------------------------------------------------------
__global__ void repack_w_kernel(const float* __restrict__ src,
                                __hip_bfloat16* __restrict__ dst, int O, int C) {
    int t = blockIdx.x * blockDim.x + threadIdx.x;
    if (t >= O * C * 9) return;
    int e   = t & 7;
    int r   = t >> 3;
    int n   = r % O;
    int q   = r / O;
    int SEG = C >> 3;
    int sg  = q % SEG;
    int tap = q / SEG;
    dst[t] = __float2bfloat16(src[(n * C + sg * 8 + e) * 9 + tap]);
}

// ---------------------------------------------------------------------------
// conv1: fp32 NCHW [CHI,3,128,128] -> bf16 padded NHWC [CHI,65,65,64], ReLU
// ---------------------------------------------------------------------------
__global__ __launch_bounds__(256) void conv1_kernel(
    const float* __restrict__ in, const float* __restrict__ wt /*[27][64]*/,
    const float* __restrict__ bias, __hip_bfloat16* __restrict__ out) {
    const int tid  = threadIdx.x;
    const int lane = tid & 63;          // ow
    const int wv   = tid >> 6;          // oc group 0..3
    const int oh   = blockIdx.x;        // 0..63
    const int b    = blockIdx.y;

    __shared__ float  sx[3][3][132];
    __shared__ ushort sc[64][72];

    const float* ip  = in + (size_t)b * 3 * 128 * 128;
    const int    ih0 = 2 * oh - 1;
    for (int e = tid; e < 1170; e += 256) {
        int c   = e / 390;
        int rem = e - c * 390;
        int r   = rem / 130;
        int col = rem - r * 130;
        int ih  = ih0 + r;
        int iw  = col - 1;
        bool ok = ((unsigned)ih < 128u) && ((unsigned)iw < 128u);
        sx[c][r][col] = ok ? ip[c * 16384 + ih * 128 + iw] : 0.f;
    }
    __syncthreads();

    const int oc0 = __builtin_amdgcn_readfirstlane(wv << 4);
    const float* wts = wt + oc0;
    float acc[16];
#pragma unroll
    for (int i = 0; i < 16; ++i) acc[i] = bias[oc0 + i];
#pragma unroll
    for (int c = 0; c < 3; ++c)
#pragma unroll
        for (int kh = 0; kh < 3; ++kh)
#pragma unroll
            for (int kw = 0; kw < 3; ++kw) {
                float x = sx[c][kh][2 * lane + kw];
                const float* wrow = wts + (c * 9 + kh * 3 + kw) * 64;
#pragma unroll
                for (int i = 0; i < 16; ++i) acc[i] = fmaf(x, wrow[i], acc[i]);
            }

#pragma unroll
    for (int h = 0; h < 2; ++h) {
        union { uint4 u4; ushort s[8]; } pk;
#pragma unroll
        for (int e = 0; e < 8; ++e)
            pk.s[e] = bf16_bits(fmaxf(acc[h * 8 + e], 0.f));
        *(uint4*)&sc[lane][oc0 + h * 8] = pk.u4;
    }
    __syncthreads();

    __hip_bfloat16* obase = out + (((size_t)b * 65 + oh + 1) * 65 + 1) * 64;
#pragma unroll
    for (int s = 0; s < 2; ++s) {
        int g   = tid * 32 + s * 16;
        int pix = g >> 7;
        int col = (g & 127) >> 1;
        uint4 val = *(const uint4*)&sc[pix][col];
        *(uint4*)((char*)obase + g) = val;
    }
}

// ---------------------------------------------------------------------------
// conv2 implicit-GEMM, barrier-free tap loop: A-region staged once per
// 32-ch half ((p>>1)-swizzled), B coalesced from repacked [tap][sg][128][8].
// M-tile 128 (4 oh x 32 ow), N = 128.
// ---------------------------------------------------------------------------
__global__ __launch_bounds__(256, 2) void conv2_gemm_kernel(
    const __hip_bfloat16* __restrict__ act,
    const __hip_bfloat16* __restrict__ wtB,   // [tap][8][128][8]
    const float* __restrict__ bias,
    __hip_bfloat16* __restrict__ out) {
    const int tid  = threadIdx.x;
    const int lane = tid & 63;
    const int w    = tid >> 6;
    const int l15  = lane & 15;
    const int quad = lane >> 4;
    const int per  = gridDim.x >> 3;
    const int Mt   = (blockIdx.x & 7) * per + (blockIdx.x >> 3);
    const int bimg = Mt >> 3;
    const int oh0  = (Mt & 7) << 2;

    __shared__ __align__(16) char smem[37504];   // 585 px * 64 B
    ushort* As = (ushort*)smem;
    ushort* Cs = (ushort*)smem;                  // epilogue alias

    f32x4 acc[4][4];
#pragma unroll
    for (int i = 0; i < 4; ++i)
#pragma unroll
        for (int j = 0; j < 4; ++j) acc[i][j] = (f32x4){0.f, 0.f, 0.f, 0.f};

    const int wm = (w & 1) << 6;
    const int wn = (w >> 1) << 6;
    const size_t abase = ((size_t)(bimg * 65 + 2 * oh0)) * 65 * 64;

    for (int h = 0; h < 2; ++h) {
        __syncthreads();   // previous pass's LDS reads complete
        // stage 9 rows x 65 px x 32 ch = 2340 16B chunks
#pragma unroll
        for (int it = 0; it < 10; ++it) {
            int e = tid + (it << 8);
            if (e < 2340) {
                int s = e & 3, p = e >> 2;            // p = r*65 + px
                uint4 val = *(const uint4*)(act + abase + (size_t)p * 64 +
                                            h * 32 + s * 8);
                *(uint4*)(As + p * 32 + (((s ^ (p >> 1)) & 3) << 3)) = val;
            }
        }
        __syncthreads();
#pragma unroll
        for (int tap = 0; tap < 9; ++tap) {
            const int kh = tap / 3, kw = tap - kh * 3;
            short8 af[4], bf[4];
#pragma unroll
            for (int i = 0; i < 4; ++i) {
                int ml = wm + i * 16 + l15;
                int p  = ((ml >> 5) * 2 + kh) * 65 + ((ml & 31) * 2 + kw);
                af[i] = __builtin_bit_cast(short8,
                    *(const uint4*)(As + p * 32 + (((quad ^ (p >> 1)) & 3) << 3)));
            }
#pragma unroll
            for (int j = 0; j < 4; ++j)
                bf[j] = __builtin_bit_cast(short8,
                    *(const uint4*)(wtB +
                        ((size_t)((tap * 8 + h * 4 + quad) * 128) +
                         wn + j * 16 + l15) * 8));
#pragma unroll
            for (int i = 0; i < 4; ++i)
#pragma unroll
                for (int j = 0; j < 4; ++j)
                    acc[i][j] = __builtin_amdgcn_mfma_f32_16x16x32_bf16(
                        af[i], bf[j], acc[i][j], 0, 0, 0);
        }
    }

    // epilogue: bias+ReLU -> bf16 tile in LDS -> coalesced 8B stores
    __syncthreads();
#pragma unroll
    for (int j = 0; j < 4; ++j) {
        int n = wn + j * 16 + l15;
        float bv = bias[n];
#pragma unroll
        for (int i = 0; i < 4; ++i)
#pragma unroll
            for (int r = 0; r < 4; ++r) {
                int ml = wm + i * 16 + quad * 4 + r;
                Cs[ml * 132 + n] = bf16_bits(fmaxf(acc[i][j][r] + bv, 0.f));
            }
    }
    __syncthreads();
#pragma unroll
    for (int q = 0; q < 16; ++q) {
        int c   = tid + 256 * q;
        int row = c >> 5;
        int off = c & 31;
        uint2 val = *(const uint2*)(Cs + row * 132 + off * 4);
        int m  = (Mt << 7) + row;
        int b  = m >> 10;
        int rr = m & 1023;
        int oh = rr >> 5;
        int ow = rr & 31;
        size_t pix = ((size_t)(b * 33 + oh + 1) * 33 + (ow + 1));
        *(uint2*)(out + pix * 128 + off * 4) = val;
    }
}

// ---------------------------------------------------------------------------
// conv3 implicit-GEMM + fused pool: A-region per 64-ch half ((p>>1)-swizzle,
// conflict-free), B coalesced from [tap][16][256][8]. Tap loop NOT unrolled
// (caps live ranges; r10's full unroll spilled). M-tile 64, N = 256.
// ---------------------------------------------------------------------------
__global__ __launch_bounds__(256, 2) void conv3_gemm_pool_kernel(
    const __hip_bfloat16* __restrict__ act,
    const __hip_bfloat16* __restrict__ wtB,   // [tap][16][256][8]
    const float* __restrict__ bias,
    float* __restrict__ v /* [CHI,256], pre-zeroed */) {
    const int tid  = threadIdx.x;
    const int lane = tid & 63;
    const int w    = tid >> 6;
    const int l15  = lane & 15;
    const int quad = lane >> 4;
    const int per  = gridDim.x >> 3;
    const int Mt   = (blockIdx.x & 7) * per + (blockIdx.x >> 3);
    const int bimg = Mt >> 2;
    const int oh0  = (Mt & 3) << 2;

    __shared__ __align__(16) char smem[38016];   // 297 px * 128 B
    ushort* As   = (ushort*)smem;
    float*  sred = (float*)smem;                 // pool alias (1 KB)

    f32x4 acc[4][4];
#pragma unroll
    for (int i = 0; i < 4; ++i)
#pragma unroll
        for (int j = 0; j < 4; ++j) acc[i][j] = (f32x4){0.f, 0.f, 0.f, 0.f};

    const int wn = w << 6;                       // wave owns 64 n-cols
    const size_t abase = ((size_t)(bimg * 33 + 2 * oh0)) * 33 * 128;

    for (int h = 0; h < 2; ++h) {
        __syncthreads();
        // stage 9 rows x 33 px x 64 ch = 2376 16B chunks
#pragma unroll
        for (int it = 0; it < 10; ++it) {
            int e = tid + (it << 8);
            if (e < 2376) {
                int s = e & 7, p = e >> 3;           // p = r*33 + px
                uint4 val = *(const uint4*)(act + abase + (size_t)p * 128 +
                                            h * 64 + s * 8);
                *(uint4*)(As + p * 64 + (((s ^ (p >> 1)) & 7) << 3)) = val;
            }
        }
        __syncthreads();
#pragma unroll 1
        for (int tap = 0; tap < 9; ++tap) {
            const int kh = tap / 3, kw = tap - kh * 3;
#pragma unroll
            for (int ks = 0; ks < 2; ++ks) {
                short8 af[4], bf[4];
                const int sl = ks * 4 + quad;        // seg within 64-ch half
#pragma unroll
                for (int i = 0; i < 4; ++i) {
                    int p = (i * 2 + kh) * 33 + l15 * 2 + kw;
                    af[i] = __builtin_bit_cast(short8,
                        *(const uint4*)(As + p * 64 +
                                        (((sl ^ (p >> 1)) & 7) << 3)));
                }
#pragma unroll
                for (int j = 0; j < 4; ++j)
                    bf[j] = __builtin_bit_cast(short8,
                        *(const uint4*)(wtB +
                            ((size_t)((tap * 16 + h * 8 + sl) * 256) +
                             wn + j * 16 + l15) * 8));
#pragma unroll
                for (int i = 0; i < 4; ++i)
#pragma unroll
                    for (int j = 0; j < 4; ++j)
                        acc[i][j] = __builtin_amdgcn_mfma_f32_16x16x32_bf16(
                            af[i], bf[j], acc[i][j], 0, 0, 0);
            }
        }
    }

    // fused pool: bias+ReLU, sum over the block's 64 spatial positions
    float s4[4];
#pragma unroll
    for (int j = 0; j < 4; ++j) {
        float bv = bias[wn + j * 16 + l15];
        float s = 0.f;
#pragma unroll
        for (int i = 0; i < 4; ++i)
#pragma unroll
            for (int r = 0; r < 4; ++r)
                s += fmaxf(acc[i][j][r] + bv, 0.f);
        s += __shfl_xor(s, 16, 64);   // reduce across quads (same n)
        s += __shfl_xor(s, 32, 64);
        s4[j] = s;
    }
    __syncthreads();   // all K-loop LDS reads done before sred alias write
    if (quad == 0) {
#pragma unroll
        for (int j = 0; j < 4; ++j) sred[wn + j * 16 + l15] = s4[j];
    }
    __syncthreads();
    atomicAdd(v + (size_t)bimg * 256 + tid, sred[tid] * (1.f / 256.f));
}

// ---------------------------------------------------------------------------
// Tail: one block (256 thr) per sample; K-split GEMV stages, float4 weights.
// ---------------------------------------------------------------------------
template<int N, int K, int S, bool RELU>
__device__ __forceinline__ void gemv_stage(const float* __restrict__ w,
                                           const float* __restrict__ bias,
                                           const float* in, float* outv,
                                           float4* red4, int tid) {
    constexpr int G = N / 4;
    constexpr int CHK = K / S;
    static_assert(G * S == 256 && CHK * S == K, "stage shape");
    const int g = tid % G, s = tid / G;
    const float4* wp = (const float4*)w;
    float4 a; a.x = a.y = a.z = a.w = 0.f;
    const int k0 = s * CHK;
#pragma unroll 8
    for (int i = 0; i < CHK; ++i) {
        float x = in[k0 + i];
        float4 wv = wp[(size_t)(k0 + i) * G + g];
        a.x = fmaf(x, wv.x, a.x);
        a.y = fmaf(x, wv.y, a.y);
        a.z = fmaf(x, wv.z, a.z);
        a.w = fmaf(x, wv.w, a.w);
    }
    red4[tid] = a;
    __syncthreads();
    if (tid < N) {
        int gg = tid >> 2, e = tid & 3;
        float vv = bias[tid];
#pragma unroll
        for (int ss = 0; ss < S; ++ss) {
            const float* rp = (const float*)(red4 + ss * G + gg);
            vv += rp[e];
        }
        if (RELU) vv = fmaxf(vv, 0.f);
        outv[tid] = vv;
    }
    __syncthreads();
}

__global__ __launch_bounds__(256) void tail_kernel(
    const float* __restrict__ prop, const int* __restrict__ task_ids,
    const float* __restrict__ p1_w, const float* __restrict__ p1_b,
    const float* __restrict__ p2_w, const float* __restrict__ p2_b,
    const float* __restrict__ v,
    const float* __restrict__ f1_w, const float* __restrict__ f1_b,
    const float* __restrict__ f2_w, const float* __restrict__ f2_b,
    const float* __restrict__ task_emb,
    const float* __restrict__ g_w, const float* __restrict__ g_b,
    const float* __restrict__ h1_w, const float* __restrict__ h1_b,
    const float* __restrict__ h2_w, const float* __restrict__ h2_b,
    const float* __restrict__ h3_w, const float* __restrict__ h3_b,
    float* __restrict__ out) {
    const int b   = blockIdx.x;
    const int tid = threadIdx.x;
    const int t   = task_ids[b];
    __shared__ float sa[320];
    __shared__ float sb[288];
    __shared__ float sph[64];
    __shared__ float4 red4[256];

    sa[tid] = (tid < 256) ? v[(size_t)b * 256 + tid] : 0.f;
    if (tid < 64) {
        float h = p1_b[tid];
#pragma unroll
        for (int k = 0; k < 7; ++k) h = fmaf(prop[b * 7 + k], p1_w[k * 64 + tid], h);
        sph[tid] = fmaxf(h, 0.f);
    }
    __syncthreads();
    gemv_stage<64, 64, 16, false>(p2_w, p2_b, sph, sa + 256, red4, tid);
    gemv_stage<256, 320, 4, true>(f1_w, f1_b, sa, sb, red4, tid);
    gemv_stage<256, 256, 4, true>(f2_w, f2_b, sb, sa, red4, tid);
    if (tid < 32) sa[256 + tid] = task_emb[t * 32 + tid];
    __syncthreads();
    gemv_stage<256, 288, 4, true>(g_w, g_b, sa, sb, red4, tid);
    gemv_stage<128, 256, 8, true>(h1_w + (size_t)t * 32768, h1_b + t * 128,
                                  sb, sa, red4, tid);
    gemv_stage<128, 128, 8, true>(h2_w + (size_t)t * 16384, h2_b + t * 128,
                                  sa, sb, red4, tid);
    if (tid < 128) {
        float4 wv = ((const float4*)(h3_w + (size_t)t * 512))[tid];
        float x = sb[tid];
        float r0 = x * wv.x, r1 = x * wv.y, r2 = x * wv.z, r3 = x * wv.w;
#pragma unroll
        for (int off = 1; off < 64; off <<= 1) {
            r0 += __shfl_xor(r0, off, 64);
            r1 += __shfl_xor(r1, off, 64);
            r2 += __shfl_xor(r2, off, 64);
            r3 += __shfl_xor(r3, off, 64);
        }
        if ((tid & 63) == 0) {
            float4 rv; rv.x = r0; rv.y = r1; rv.z = r2; rv.w = r3;
            red4[tid >> 6] = rv;
        }
    }
    __syncthreads();
    if (tid < 4) {
        const float* ra = (const float*)(red4 + 0);
        const float* rb = (const float*)(red4 + 1);
        out[b * 4 + tid] = ra[tid] + rb[tid] + h3_b[t * 4 + tid];
    }
}

// ---------------------------------------------------------------------------
extern "C" void kernel_launch(void* const* d_in, const int* in_sizes, int n_in,
                              void* d_out, int out_size, void* d_ws, size_t ws_size,
                              hipStream_t stream) {
    (void)in_sizes; (void)n_in; (void)out_size;
    const float* images   = (const float*)d_in[0];
    const float* prop     = (const float*)d_in[1];
    const int*   task_ids = (const int*)d_in[2];
    const float* c1_w = (const float*)d_in[3];
    const float* c1_b = (const float*)d_in[4];
    const float* c2_w = (const float*)d_in[5];
    const float* c2_b = (const float*)d_in[6];
    const float* c3_w = (const float*)d_in[7];
    const float* c3_b = (const float*)d_in[8];
    const float* p1_w = (const float*)d_in[9];
    const float* p1_b = (const float*)d_in[10];
    const float* p2_w = (const float*)d_in[11];
    const float* p2_b = (const float*)d_in[12];
    const float* f1_w = (const float*)d_in[13];
    const float* f1_b = (const float*)d_in[14];
    const float* f2_w = (const float*)d_in[15];
    const float* f2_b = (const float*)d_in[16];
    const float* temb = (const float*)d_in[17];
    const float* g_w  = (const float*)d_in[18];
    const float* g_b  = (const float*)d_in[19];
    const float* h1_w = (const float*)d_in[20];
    const float* h1_b = (const float*)d_in[21];
    const float* h2_w = (const float*)d_in[22];
    const float* h2_b = (const float*)d_in[23];
    const float* h3_w = (const float*)d_in[24];
    const float* h3_b = (const float*)d_in[25];
    float* out = (float*)d_out;

    const size_t per_img = (size_t)65 * 65 * 64 * 2 + (size_t)33 * 33 * 128 * 2;
    const size_t fixed   = (size_t)256 * 256 * 4 + 1728 * 4 +
                           (size_t)73728 * 2 + (size_t)294912 * 2 + 4096;
    int CHI = 64;
    if (ws_size >= fixed + per_img * 256) CHI = 256;
    else if (ws_size >= fixed + per_img * 128) CHI = 128;

    char* ws = (char*)d_ws;
    size_t off = 0;
    auto alloc = [&](size_t bytes) {
        void* p = ws + off;
        off += (bytes + 255) & ~(size_t)255;
        return p;
    };
    __hip_bfloat16* act1 = (__hip_bfloat16*)alloc((size_t)CHI * 65 * 65 * 64 * 2);
    __hip_bfloat16* act2 = (__hip_bfloat16*)alloc((size_t)CHI * 33 * 33 * 128 * 2);
    float*          vbuf = (float*)alloc((size_t)256 * 256 * 4);
    float*          w1t  = (float*)alloc((size_t)1728 * 4);
    __hip_bfloat16* w2t  = (__hip_bfloat16*)alloc((size_t)73728 * 2);
    __hip_bfloat16* w3t  = (__hip_bfloat16*)alloc((size_t)294912 * 2);

    halo_zero_kernel<<<dim3(CHI), 256, 0, stream>>>(
        (uint4*)act1, (uint4*)act2, (float4*)vbuf);
    transpose_w1_kernel<<<DIV_UP(1728, 256), 256, 0, stream>>>(c1_w, w1t);
    repack_w_kernel<<<DIV_UP(73728, 256), 256, 0, stream>>>(c2_w, w2t, 128, 64);
    repack_w_kernel<<<DIV_UP(294912, 256), 256, 0, stream>>>(c3_w, w3t, 256, 128);

    for (int c0 = 0; c0 < 256; c0 += CHI) {
        const float* img_c = images + (size_t)c0 * 3 * 128 * 128;
        conv1_kernel<<<dim3(64, CHI), dim3(256), 0, stream>>>(
            img_c, w1t, c1_b, act1);
        conv2_gemm_kernel<<<dim3(CHI * 8), 256, 0, stream>>>(
            act1, w2t, c2_b, act2);
        conv3_gemm_pool_kernel<<<dim3(CHI * 4), 256, 0, stream>>>(
            act2, w3t, c3_b, vbuf + (size_t)c0 * 256);
    }
    tail_kernel<<<256, 256, 0, stream>>>(prop, task_ids, p1_w, p1_b, p2_w, p2_b,
                                         vbuf, f1_w, f1_b, f2_w, f2_b, temb,
                                         g_w, g_b, h1_w, h1_b, h2_w, h2_b,
                                         h3_w, h3_b, out);
}